// Round 1
// baseline (17792.847 us; speedup 1.0000x reference)
//
#include <hip/hip_runtime.h>
#include <hip/hip_bf16.h>

// Problem constants
#define B_ 128
#define T_ 1024
#define D_ 512
#define H_ 256
#define G_ 1024   // 4*H

typedef __bf16 bf16_t;
typedef __bf16 bf16x8 __attribute__((ext_vector_type(8)));
typedef __bf16 bf16x4 __attribute__((ext_vector_type(4)));
typedef float  f32x4  __attribute__((ext_vector_type(4)));

__device__ __forceinline__ float fast_rcp(float x) { return __builtin_amdgcn_rcpf(x); }

__device__ __forceinline__ float sigmoid_f(float x) {
  // x << 0: expf(-x) -> inf -> rcp -> 0 (correct limit)
  return fast_rcp(1.0f + __expf(-x));
}
__device__ __forceinline__ float tanh_f(float x) {
  x = fminf(fmaxf(x, -15.0f), 15.0f);   // avoid inf/inf NaN
  float e = __expf(-2.0f * x);
  return (1.0f - e) * fast_rcp(1.0f + e);
}

// ---------------------------------------------------------------------------
// prep: W_hh fp32 -> bf16, bias = b_ih + b_hh
// ---------------------------------------------------------------------------
__global__ __launch_bounds__(256) void prep_kernel(
    const float* __restrict__ Whh, const float* __restrict__ bih,
    const float* __restrict__ bhh, bf16_t* __restrict__ whhb,
    float* __restrict__ bias) {
  int i = blockIdx.x * 256 + threadIdx.x;
  if (i < G_ * H_) whhb[i] = (bf16_t)Whh[i];
  if (i < G_) bias[i] = bih[i] + bhh[i];
}

// ---------------------------------------------------------------------------
// xg = X @ W_ih^T + (b_ih + b_hh), stored bf16 [B][T][G]
// 64x64 tile / block, 4 waves, 16x16x32 bf16 MFMA, inline fp32->bf16 staging.
// ---------------------------------------------------------------------------
__global__ __launch_bounds__(256) void xg_gemm(
    const float* __restrict__ X, const float* __restrict__ Wih,
    const float* __restrict__ bias, bf16_t* __restrict__ xg) {
  // pad rows to 80 elems (160 B): 16B-aligned rows, mild 4-way bank aliasing
  __shared__ __align__(16) bf16_t As[64][80];
  __shared__ __align__(16) bf16_t Bs[64][80];

  const int tid = threadIdx.x;
  const int lane = tid & 63;
  const int w = tid >> 6;        // wave 0..3 -> M-rows 16w..16w+15
  const int q = lane >> 4;       // quad
  const int l15 = lane & 15;
  const int m0 = blockIdx.x * 64;
  const int n0 = blockIdx.y * 64;

  f32x4 acc[4];
  #pragma unroll
  for (int nt = 0; nt < 4; ++nt) acc[nt] = (f32x4){0.f, 0.f, 0.f, 0.f};

  for (int kt = 0; kt < 8; ++kt) {
    const int k0 = kt * 64;
    __syncthreads();
    // stage 64x64 A-tile and B-tile (fp32 global -> bf16 LDS), coalesced float4
    #pragma unroll
    for (int i = 0; i < 4; ++i) {
      int f = tid + 256 * i;     // 0..1023 float4 slots
      int r = f >> 4;            // row 0..63
      int c4 = f & 15;           // float4 col
      float4 va = *(const float4*)(X + (size_t)(m0 + r) * D_ + k0 + c4 * 4);
      float4 vb = *(const float4*)(Wih + (size_t)(n0 + r) * D_ + k0 + c4 * 4);
      *(bf16x4*)&As[r][c4 * 4] =
          (bf16x4){(bf16_t)va.x, (bf16_t)va.y, (bf16_t)va.z, (bf16_t)va.w};
      *(bf16x4*)&Bs[r][c4 * 4] =
          (bf16x4){(bf16_t)vb.x, (bf16_t)vb.y, (bf16_t)vb.z, (bf16_t)vb.w};
    }
    __syncthreads();
    #pragma unroll
    for (int kk = 0; kk < 2; ++kk) {
      // A-frag: m = lane&15, k = quad*8 + j
      bf16x8 a = *(const bf16x8*)&As[16 * w + l15][kk * 32 + q * 8];
      #pragma unroll
      for (int nt = 0; nt < 4; ++nt) {
        bf16x8 b = *(const bf16x8*)&Bs[16 * nt + l15][kk * 32 + q * 8];
        acc[nt] = __builtin_amdgcn_mfma_f32_16x16x32_bf16(a, b, acc[nt], 0, 0, 0);
      }
    }
  }
  // epilogue: C/D layout col=lane&15, row=quad*4+reg  [m89-verified]
  #pragma unroll
  for (int nt = 0; nt < 4; ++nt) {
    int col = n0 + nt * 16 + l15;
    float bv = bias[col];
    #pragma unroll
    for (int i = 0; i < 4; ++i) {
      int row = m0 + 16 * w + 4 * q + i;
      xg[(size_t)row * G_ + col] = (bf16_t)(acc[nt][i] + bv);
    }
  }
}

// ---------------------------------------------------------------------------
// LSTM scan: 16 WGs x 8 batch rows, 8 waves/WG.
// Wave w, pair p handles channels [32w+16p, 32w+16p+16):
//   gate tiles {q, q+16, q+32, q+48} with q = 2w+p  => i/f/g/o for a channel
//   land in the SAME lane/reg slot -> lane-local cell update, c stays in VGPRs.
// h round-trips through LDS (double-buffered, A-operand layout), W_hh streams
// from L2 every step (R1; R2 will make it resident).
// ---------------------------------------------------------------------------
__global__ __launch_bounds__(512) void lstm_scan(
    const bf16_t* __restrict__ xg, const bf16_t* __restrict__ Whh,
    float* __restrict__ hT) {
  // 264 = 256 + 8 pad: rows stay 16B-aligned (528 B), 2-way banks (free)
  __shared__ __align__(16) bf16_t hbuf[2][16][264];

  const int tid = threadIdx.x;
  const int lane = tid & 63;
  const int w = tid >> 6;        // wave 0..7
  const int q = lane >> 4;
  const int l15 = lane & 15;
  const int b0 = blockIdx.x * 8; // batch rows b0..b0+7 (tile rows 8..15 unused, stay 0)

  for (int i = tid; i < 2 * 16 * 264; i += 512) ((bf16_t*)hbuf)[i] = (bf16_t)0.0f;
  __syncthreads();

  float cst[2][4];
  #pragma unroll
  for (int p = 0; p < 2; ++p)
    #pragma unroll
    for (int i = 0; i < 4; ++i) cst[p][i] = 0.0f;

  for (int t = 0; t < T_; ++t) {
    const int cur = t & 1;
    #pragma unroll 1
    for (int p = 0; p < 2; ++p) {
      const int c = 32 * w + 16 * p + l15;   // channel this lane produces
      f32x4 ai = (f32x4){0.f,0.f,0.f,0.f}, af = ai, ag = ai, ao = ai;
      // B-frag rows: gate row = 256*gamma + c ; k = quad*8 + j  (+32*kk)
      const bf16_t* wbase = Whh + (size_t)c * H_ + q * 8;
      #pragma unroll
      for (int kk = 0; kk < 8; ++kk) {
        bf16x8 a = *(const bf16x8*)&hbuf[cur][l15][kk * 32 + q * 8];
        bf16x8 bi = *(const bf16x8*)(wbase + 0 * 256 * H_ + kk * 32);
        bf16x8 bf = *(const bf16x8*)(wbase + 1 * 256 * H_ + kk * 32);
        bf16x8 bg = *(const bf16x8*)(wbase + 2 * 256 * H_ + kk * 32);
        bf16x8 bo = *(const bf16x8*)(wbase + 3 * 256 * H_ + kk * 32);
        ai = __builtin_amdgcn_mfma_f32_16x16x32_bf16(a, bi, ai, 0, 0, 0);
        af = __builtin_amdgcn_mfma_f32_16x16x32_bf16(a, bf, af, 0, 0, 0);
        ag = __builtin_amdgcn_mfma_f32_16x16x32_bf16(a, bg, ag, 0, 0, 0);
        ao = __builtin_amdgcn_mfma_f32_16x16x32_bf16(a, bo, ao, 0, 0, 0);
      }
      if (q < 2) {               // rows 0..7 valid (NB=8)
        const bf16_t* xgp = xg + ((size_t)(b0 + 4 * q) * T_ + t) * G_ + c;
        #pragma unroll
        for (int i = 0; i < 4; ++i) {
          const bf16_t* xr = xgp + (size_t)i * T_ * G_;
          float gi = ai[i] + (float)xr[0 * H_];
          float gf = af[i] + (float)xr[1 * H_];
          float gg = ag[i] + (float)xr[2 * H_];
          float go = ao[i] + (float)xr[3 * H_];
          float I = sigmoid_f(gi);
          float F = sigmoid_f(gf);
          float Gv = tanh_f(gg);
          float Ov = sigmoid_f(go);
          float cv = F * cst[p][i] + I * Gv;
          cst[p][i] = cv;
          float hv = Ov * tanh_f(cv);
          hbuf[cur ^ 1][4 * q + i][c] = (bf16_t)hv;
          if (t == T_ - 1) hT[(size_t)(b0 + 4 * q + i) * H_ + c] = hv;
        }
      }
    }
    // one barrier/step: writes go to buf (cur^1); next step's writes to buf cur
    // can only happen after every wave passed this barrier (= finished reading cur)
    __syncthreads();
  }
}

// ---------------------------------------------------------------------------
// out = h_T @ W_out^T + b_out   [128,256]x[256,128] -> tiny
// ---------------------------------------------------------------------------
__global__ __launch_bounds__(128) void head_gemm(
    const float* __restrict__ hT, const float* __restrict__ Wout,
    const float* __restrict__ bout, float* __restrict__ out) {
  __shared__ float hrow[H_];
  const int b = blockIdx.x;
  const int o = threadIdx.x;
  hrow[o] = hT[(size_t)b * H_ + o];
  hrow[o + 128] = hT[(size_t)b * H_ + 128 + o];
  __syncthreads();
  float s = bout[o];
  const float* wr = Wout + (size_t)o * H_;
  #pragma unroll 8
  for (int j = 0; j < H_; ++j) s += hrow[j] * wr[j];
  out[(size_t)b * 128 + o] = s;
}

// ---------------------------------------------------------------------------
extern "C" void kernel_launch(void* const* d_in, const int* in_sizes, int n_in,
                              void* d_out, int out_size, void* d_ws, size_t ws_size,
                              hipStream_t stream) {
  const float* X    = (const float*)d_in[0];
  const float* Wih  = (const float*)d_in[1];
  const float* Whh  = (const float*)d_in[2];
  const float* bih  = (const float*)d_in[3];
  const float* bhh  = (const float*)d_in[4];
  const float* Wout = (const float*)d_in[5];
  const float* bout = (const float*)d_in[6];
  float* out = (float*)d_out;

  // workspace layout (bytes)
  char* ws = (char*)d_ws;
  const size_t XG_BYTES   = (size_t)B_ * T_ * G_ * 2;        // 268435456
  const size_t WHHB_BYTES = (size_t)G_ * H_ * 2;             // 524288
  const size_t BIAS_BYTES = (size_t)G_ * 4;                  // 4096
  bf16_t* xg   = (bf16_t*)ws;
  bf16_t* whhb = (bf16_t*)(ws + XG_BYTES);
  float*  bias = (float*)(ws + XG_BYTES + WHHB_BYTES);
  float*  hT   = (float*)(ws + XG_BYTES + WHHB_BYTES + BIAS_BYTES);

  prep_kernel<<<dim3(1024), 256, 0, stream>>>(Whh, bih, bhh, whhb, bias);
  xg_gemm<<<dim3((B_ * T_) / 64, G_ / 64), 256, 0, stream>>>(X, Wih, bias, xg);
  lstm_scan<<<dim3(B_ / 8), 512, 0, stream>>>(xg, whhb, hT);
  head_gemm<<<dim3(B_), 128, 0, stream>>>(hT, Wout, bout, out);
}

// Round 2
// 4532.207 us; speedup vs baseline: 3.9259x; 3.9259x over previous
//
#include <hip/hip_runtime.h>
#include <hip/hip_bf16.h>

// Problem constants
#define B_ 128
#define T_ 1024
#define D_ 512
#define H_ 256
#define G_ 1024   // 4*H

typedef __bf16 bf16_t;
typedef __bf16 bf16x8 __attribute__((ext_vector_type(8)));
typedef __bf16 bf16x4 __attribute__((ext_vector_type(4)));
typedef float  f32x4  __attribute__((ext_vector_type(4)));

__device__ __forceinline__ float fast_rcp(float x) { return __builtin_amdgcn_rcpf(x); }

__device__ __forceinline__ float sigmoid_f(float x) {
  return fast_rcp(1.0f + __expf(-x));
}
__device__ __forceinline__ float tanh_f(float x) {
  x = fminf(fmaxf(x, -15.0f), 15.0f);   // avoid inf/inf NaN
  float e = __expf(-2.0f * x);
  return (1.0f - e) * fast_rcp(1.0f + e);
}

// ---------------------------------------------------------------------------
// prep: W_hh fp32 -> bf16, bias = b_ih + b_hh
// ---------------------------------------------------------------------------
__global__ __launch_bounds__(256) void prep_kernel(
    const float* __restrict__ Whh, const float* __restrict__ bih,
    const float* __restrict__ bhh, bf16_t* __restrict__ whhb,
    float* __restrict__ bias) {
  int i = blockIdx.x * 256 + threadIdx.x;
  if (i < G_ * H_) whhb[i] = (bf16_t)Whh[i];
  if (i < G_) bias[i] = bih[i] + bhh[i];
}

// ---------------------------------------------------------------------------
// xg2[row][c][gamma] = (X @ W_ih^T + b)[row][gamma*256+c], bf16, row = b*T+t.
// Block: 64 rows x (4 gates x 16 channels). N-tile nt == gate gamma, so the
// epilogue packs the 4 gate values of one (row, c) into one coalesced 8 B store.
// ---------------------------------------------------------------------------
__global__ __launch_bounds__(256) void xg_gemm(
    const float* __restrict__ X, const float* __restrict__ Wih,
    const float* __restrict__ bias, bf16_t* __restrict__ xg2) {
  __shared__ __align__(16) bf16_t As[64][80];
  __shared__ __align__(16) bf16_t Bs[64][80];

  const int tid = threadIdx.x;
  const int lane = tid & 63;
  const int w = tid >> 6;        // wave 0..3 -> M-rows 16w..16w+15
  const int q = lane >> 4;       // quad
  const int l15 = lane & 15;
  const int m0 = blockIdx.x * 64;
  const int n0p = blockIdx.y * 16;   // channel tile within H (0..255)

  f32x4 acc[4];
  #pragma unroll
  for (int nt = 0; nt < 4; ++nt) acc[nt] = (f32x4){0.f, 0.f, 0.f, 0.f};

  for (int kt = 0; kt < 8; ++kt) {
    const int k0 = kt * 64;
    __syncthreads();
    #pragma unroll
    for (int i = 0; i < 4; ++i) {
      int f = tid + 256 * i;     // 0..1023 float4 slots
      int r = f >> 4;            // row 0..63
      int c4 = f & 15;           // float4 col
      // B row r -> Wih row gate(r>>4)*256 + n0p + (r&15)
      int wr = ((r >> 4) << 8) + n0p + (r & 15);
      float4 va = *(const float4*)(X + (size_t)(m0 + r) * D_ + k0 + c4 * 4);
      float4 vb = *(const float4*)(Wih + (size_t)wr * D_ + k0 + c4 * 4);
      *(bf16x4*)&As[r][c4 * 4] =
          (bf16x4){(bf16_t)va.x, (bf16_t)va.y, (bf16_t)va.z, (bf16_t)va.w};
      *(bf16x4*)&Bs[r][c4 * 4] =
          (bf16x4){(bf16_t)vb.x, (bf16_t)vb.y, (bf16_t)vb.z, (bf16_t)vb.w};
    }
    __syncthreads();
    #pragma unroll
    for (int kk = 0; kk < 2; ++kk) {
      bf16x8 a = *(const bf16x8*)&As[16 * w + l15][kk * 32 + q * 8];
      #pragma unroll
      for (int nt = 0; nt < 4; ++nt) {
        bf16x8 b = *(const bf16x8*)&Bs[16 * nt + l15][kk * 32 + q * 8];
        acc[nt] = __builtin_amdgcn_mfma_f32_16x16x32_bf16(a, b, acc[nt], 0, 0, 0);
      }
    }
  }
  // epilogue: C/D layout col=lane&15 (channel), row=quad*4+reg (m)
  const int cc = n0p + l15;
  float bv0 = bias[cc], bv1 = bias[256 + cc], bv2 = bias[512 + cc], bv3 = bias[768 + cc];
  #pragma unroll
  for (int i = 0; i < 4; ++i) {
    int row = m0 + 16 * w + 4 * q + i;
    bf16x4 v = (bf16x4){(bf16_t)(acc[0][i] + bv0), (bf16_t)(acc[1][i] + bv1),
                        (bf16_t)(acc[2][i] + bv2), (bf16_t)(acc[3][i] + bv3)};
    *(bf16x4*)(xg2 + ((size_t)row * 256 + cc) * 4) = v;
  }
}

// ---------------------------------------------------------------------------
// LSTM scan: 8 WGs x 16 batch rows, 8 waves/WG, W_hh fully on-chip:
//   48 B-frags/wave in VGPRs (192 VGPRs) + 16 frags/wave in LDS (128 KB).
// Wave w handles channels [32w, 32w+32) as two phases p=0,1 (c = 32w+16p+l15).
// Per phase: 32 MFMA (4 gates x 8 K-steps), then lane-local cell update
// (C/D layout: row=4q+i, col=l15). h double-buffered in LDS, 1 barrier/step.
// xg prefetched one full step ahead as one bf16x4 (4 gates) per (row,phase).
// ---------------------------------------------------------------------------
__global__ __launch_bounds__(512, 2) void lstm_scan(
    const bf16_t* __restrict__ xg2, const bf16_t* __restrict__ Whh,
    float* __restrict__ hT) {
  __shared__ __align__(16) bf16_t wlds[8 * 16 * 512];   // 128 KB: [w][frag][lane*8]
  __shared__ __align__(16) bf16_t hbuf[2][16][264];     // 16.9 KB, double-buffered

  const int tid = threadIdx.x;
  const int lane = tid & 63;
  const int w = tid >> 6;        // wave 0..7
  const int q = lane >> 4;
  const int l15 = lane & 15;
  const int b0 = blockIdx.x * 16;

  // ---- load W_hh: 6 (p,gate) sets -> VGPRs, (p=1, g=2,3) -> LDS ----
  bf16x8 wreg[6][8];
  #pragma unroll
  for (int p2 = 0; p2 < 2; ++p2) {
    #pragma unroll
    for (int g2 = 0; g2 < 4; ++g2) {
      const int j = p2 * 4 + g2;
      const bf16_t* src =
          Whh + (size_t)(g2 * 256 + 32 * w + 16 * p2 + l15) * H_ + q * 8;
      #pragma unroll
      for (int kk = 0; kk < 8; ++kk) {
        bf16x8 v = *(const bf16x8*)(src + kk * 32);
        if (j < 6) {
          wreg[j][kk] = v;
        } else {
          *(bf16x8*)&wlds[(size_t)((w * 16 + (g2 - 2) * 8 + kk)) * 512 + lane * 8] = v;
        }
      }
    }
  }

  for (int i = tid; i < 2 * 16 * 264; i += 512) ((bf16_t*)hbuf)[i] = (bf16_t)0.0f;
  __syncthreads();

  float cst[2][4];
  #pragma unroll
  for (int p = 0; p < 2; ++p)
    #pragma unroll
    for (int i = 0; i < 4; ++i) cst[p][i] = 0.0f;

  // xg bases: one per reg-row i; elem idx = row_g*1024 + c*4 + gamma
  const bf16_t* xb[4];
  #pragma unroll
  for (int i = 0; i < 4; ++i)
    xb[i] = xg2 + (size_t)(b0 + 4 * q + i) * (size_t)T_ * 1024 + (32 * w + l15) * 4;

  bf16x4 xv[2][4];
  #pragma unroll
  for (int p = 0; p < 2; ++p)
    #pragma unroll
    for (int i = 0; i < 4; ++i)
      xv[p][i] = *(const bf16x4*)(xb[i] + p * 64);

  #pragma unroll 1
  for (int t = 0; t < T_; ++t) {
    const int cur = t & 1;
    #pragma unroll
    for (int p = 0; p < 2; ++p) {
      f32x4 acc[4];
      #pragma unroll
      for (int g = 0; g < 4; ++g) acc[g] = (f32x4){0.f, 0.f, 0.f, 0.f};
      #pragma unroll
      for (int kk = 0; kk < 8; ++kk) {
        bf16x8 a = *(const bf16x8*)&hbuf[cur][l15][kk * 32 + q * 8];
        if (p == 0) {
          acc[0] = __builtin_amdgcn_mfma_f32_16x16x32_bf16(a, wreg[0][kk], acc[0], 0, 0, 0);
          acc[1] = __builtin_amdgcn_mfma_f32_16x16x32_bf16(a, wreg[1][kk], acc[1], 0, 0, 0);
          acc[2] = __builtin_amdgcn_mfma_f32_16x16x32_bf16(a, wreg[2][kk], acc[2], 0, 0, 0);
          acc[3] = __builtin_amdgcn_mfma_f32_16x16x32_bf16(a, wreg[3][kk], acc[3], 0, 0, 0);
        } else {
          acc[0] = __builtin_amdgcn_mfma_f32_16x16x32_bf16(a, wreg[4][kk], acc[0], 0, 0, 0);
          acc[1] = __builtin_amdgcn_mfma_f32_16x16x32_bf16(a, wreg[5][kk], acc[1], 0, 0, 0);
          bf16x8 bg = *(const bf16x8*)&wlds[(size_t)(w * 16 + kk) * 512 + lane * 8];
          bf16x8 bo = *(const bf16x8*)&wlds[(size_t)(w * 16 + 8 + kk) * 512 + lane * 8];
          acc[2] = __builtin_amdgcn_mfma_f32_16x16x32_bf16(a, bg, acc[2], 0, 0, 0);
          acc[3] = __builtin_amdgcn_mfma_f32_16x16x32_bf16(a, bo, acc[3], 0, 0, 0);
        }
      }
      const int c = 32 * w + 16 * p + l15;
      #pragma unroll
      for (int i = 0; i < 4; ++i) {
        float gi = acc[0][i] + (float)xv[p][i][0];
        float gf = acc[1][i] + (float)xv[p][i][1];
        float gg = acc[2][i] + (float)xv[p][i][2];
        float go = acc[3][i] + (float)xv[p][i][3];
        float I = sigmoid_f(gi);
        float F = sigmoid_f(gf);
        float Gv = tanh_f(gg);
        float Ov = sigmoid_f(go);
        float cv = F * cst[p][i] + I * Gv;
        cst[p][i] = cv;
        float hv = Ov * tanh_f(cv);
        hbuf[cur ^ 1][4 * q + i][c] = (bf16_t)hv;
        if (t == T_ - 1) hT[(size_t)(b0 + 4 * q + i) * H_ + c] = hv;
      }
      // prefetch next step's xg for this phase (consumed ~1 full step later).
      // t=1023 reads land harmlessly in the whhb region of d_ws.
      #pragma unroll
      for (int i = 0; i < 4; ++i)
        xv[p][i] = *(const bf16x4*)(xb[i] + (size_t)(t + 1) * 1024 + p * 64);
    }
    __syncthreads();
  }
}

// ---------------------------------------------------------------------------
// out = h_T @ W_out^T + b_out   [128,256]x[256,128] -> tiny
// ---------------------------------------------------------------------------
__global__ __launch_bounds__(128) void head_gemm(
    const float* __restrict__ hT, const float* __restrict__ Wout,
    const float* __restrict__ bout, float* __restrict__ out) {
  __shared__ float hrow[H_];
  const int b = blockIdx.x;
  const int o = threadIdx.x;
  hrow[o] = hT[(size_t)b * H_ + o];
  hrow[o + 128] = hT[(size_t)b * H_ + 128 + o];
  __syncthreads();
  float s = bout[o];
  const float* wr = Wout + (size_t)o * H_;
  #pragma unroll 8
  for (int j = 0; j < H_; ++j) s += hrow[j] * wr[j];
  out[(size_t)b * 128 + o] = s;
}

// ---------------------------------------------------------------------------
extern "C" void kernel_launch(void* const* d_in, const int* in_sizes, int n_in,
                              void* d_out, int out_size, void* d_ws, size_t ws_size,
                              hipStream_t stream) {
  const float* X    = (const float*)d_in[0];
  const float* Wih  = (const float*)d_in[1];
  const float* Whh  = (const float*)d_in[2];
  const float* bih  = (const float*)d_in[3];
  const float* bhh  = (const float*)d_in[4];
  const float* Wout = (const float*)d_in[5];
  const float* bout = (const float*)d_in[6];
  float* out = (float*)d_out;

  // workspace layout (bytes)
  char* ws = (char*)d_ws;
  const size_t XG_BYTES   = (size_t)B_ * T_ * G_ * 2;        // 268435456
  const size_t WHHB_BYTES = (size_t)G_ * H_ * 2;             // 524288
  const size_t BIAS_BYTES = (size_t)G_ * 4;                  // 4096
  bf16_t* xg2  = (bf16_t*)ws;
  bf16_t* whhb = (bf16_t*)(ws + XG_BYTES);
  float*  bias = (float*)(ws + XG_BYTES + WHHB_BYTES);
  float*  hT   = (float*)(ws + XG_BYTES + WHHB_BYTES + BIAS_BYTES);

  prep_kernel<<<dim3(1024), 256, 0, stream>>>(Whh, bih, bhh, whhb, bias);
  xg_gemm<<<dim3((B_ * T_) / 64, 16), 256, 0, stream>>>(X, Wih, bias, xg2);
  lstm_scan<<<dim3(B_ / 16), 512, 0, stream>>>(xg2, whhb, hT);
  head_gemm<<<dim3(B_), 128, 0, stream>>>(hT, Wout, bout, out);
}

// Round 3
// 3845.626 us; speedup vs baseline: 4.6268x; 1.1785x over previous
//
#include <hip/hip_runtime.h>
#include <hip/hip_bf16.h>

// Problem constants
#define B_ 128
#define T_ 1024
#define D_ 512
#define H_ 256
#define G_ 1024   // 4*H

typedef __bf16 bf16_t;
typedef __bf16 bf16x8 __attribute__((ext_vector_type(8)));
typedef __bf16 bf16x4 __attribute__((ext_vector_type(4)));
typedef float  f32x4  __attribute__((ext_vector_type(4)));

__device__ __forceinline__ float fast_rcp(float x) { return __builtin_amdgcn_rcpf(x); }

__device__ __forceinline__ float sigmoid_f(float x) {
  return fast_rcp(1.0f + __expf(-x));
}
__device__ __forceinline__ float tanh_f(float x) {
  x = fminf(fmaxf(x, -15.0f), 15.0f);   // avoid inf/inf NaN
  float e = __expf(-2.0f * x);
  return (1.0f - e) * fast_rcp(1.0f + e);
}

// Workgroup barrier that waits only on LDS ops (lgkmcnt). Unlike
// __syncthreads(), this does NOT drain vmcnt — our in-flight global loads are
// lane-private prefetches that no other thread depends on. h propagates
// through LDS, which lgkmcnt(0) covers. "memory" clobber = compiler fence.
__device__ __forceinline__ void barrier_lds_only() {
  asm volatile("s_waitcnt lgkmcnt(0)\n\ts_barrier" ::: "memory");
}

// ---------------------------------------------------------------------------
// prep: W_hh fp32 -> bf16, bias = b_ih + b_hh
// ---------------------------------------------------------------------------
__global__ __launch_bounds__(256) void prep_kernel(
    const float* __restrict__ Whh, const float* __restrict__ bih,
    const float* __restrict__ bhh, bf16_t* __restrict__ whhb,
    float* __restrict__ bias) {
  int i = blockIdx.x * 256 + threadIdx.x;
  if (i < G_ * H_) whhb[i] = (bf16_t)Whh[i];
  if (i < G_) bias[i] = bih[i] + bhh[i];
}

// ---------------------------------------------------------------------------
// xg2[row][c][gamma] = (X @ W_ih^T + b)[row][gamma*256+c], bf16, row = b*T+t.
// Block: 64 rows x 256 G-cols (64 channels x 4 gates) -> X re-read only 4x.
// B-LDS row r <-> Wih row (r>>6)*256 + ch0 + (r&63); n-tile n = gate*4 + cs.
// ---------------------------------------------------------------------------
__global__ __launch_bounds__(256) void xg_gemm(
    const float* __restrict__ X, const float* __restrict__ Wih,
    const float* __restrict__ bias, bf16_t* __restrict__ xg2) {
  __shared__ __align__(16) bf16_t As[64][72];    // 9.2 KB
  __shared__ __align__(16) bf16_t Bs[256][72];   // 36.9 KB

  const int tid = threadIdx.x;
  const int lane = tid & 63;
  const int w = tid >> 6;        // wave 0..3 -> M-rows 16w..16w+15
  const int q = lane >> 4;
  const int l15 = lane & 15;
  const int m0 = blockIdx.x * 64;
  const int ch0 = blockIdx.y * 64;   // channel tile within H

  f32x4 acc[16];
  #pragma unroll
  for (int n = 0; n < 16; ++n) acc[n] = (f32x4){0.f, 0.f, 0.f, 0.f};

  for (int kt = 0; kt < 8; ++kt) {
    const int k0 = kt * 64;
    __syncthreads();
    // A: 1024 float4 slots (64 rows x 16)
    #pragma unroll
    for (int i = 0; i < 4; ++i) {
      int f = tid + 256 * i;
      int r = f >> 4, c4 = f & 15;
      float4 va = *(const float4*)(X + (size_t)(m0 + r) * D_ + k0 + c4 * 4);
      *(bf16x4*)&As[r][c4 * 4] =
          (bf16x4){(bf16_t)va.x, (bf16_t)va.y, (bf16_t)va.z, (bf16_t)va.w};
    }
    // B: 4096 float4 slots (256 rows x 16)
    #pragma unroll
    for (int j = 0; j < 16; ++j) {
      int f = tid + 256 * j;
      int r = f >> 4, c4 = f & 15;
      int wr = (r >> 6) * 256 + ch0 + (r & 63);
      float4 vb = *(const float4*)(Wih + (size_t)wr * D_ + k0 + c4 * 4);
      *(bf16x4*)&Bs[r][c4 * 4] =
          (bf16x4){(bf16_t)vb.x, (bf16_t)vb.y, (bf16_t)vb.z, (bf16_t)vb.w};
    }
    __syncthreads();
    #pragma unroll
    for (int kk = 0; kk < 2; ++kk) {
      bf16x8 a = *(const bf16x8*)&As[16 * w + l15][kk * 32 + q * 8];
      #pragma unroll
      for (int n = 0; n < 16; ++n) {
        bf16x8 b = *(const bf16x8*)&Bs[16 * n + l15][kk * 32 + q * 8];
        acc[n] = __builtin_amdgcn_mfma_f32_16x16x32_bf16(a, b, acc[n], 0, 0, 0);
      }
    }
  }
  // epilogue: C/D layout col=lane&15, row=quad*4+reg; acc[g*4+cs]
  #pragma unroll
  for (int cs = 0; cs < 4; ++cs) {
    const int cc = ch0 + cs * 16 + l15;
    float bv0 = bias[cc], bv1 = bias[256 + cc];
    float bv2 = bias[512 + cc], bv3 = bias[768 + cc];
    #pragma unroll
    for (int i = 0; i < 4; ++i) {
      int row = m0 + 16 * w + 4 * q + i;
      bf16x4 v = (bf16x4){(bf16_t)(acc[cs][i] + bv0), (bf16_t)(acc[4 + cs][i] + bv1),
                          (bf16_t)(acc[8 + cs][i] + bv2), (bf16_t)(acc[12 + cs][i] + bv3)};
      *(bf16x4*)(xg2 + ((size_t)row * 256 + cc) * 4) = v;
    }
  }
}

// ---------------------------------------------------------------------------
// LSTM scan: 16 WGs x 8 batch rows, 8 waves/WG. W_hh on-chip (48 frags/wave
// in regs + 16 in LDS). MFMA M=16 is half-idle (rows 8..15 stay zero) - the
// deliberate trade: 2x CUs, half the per-CU cell/VALU work.
// After MFMA (C/D: row=4q+i, col=c) gates are redistributed so ALL 64 lanes
// handle 2 cells: lane (q,l15) owns rows {rq, rq+1}, rq=(q&1)*4+(q>>1)*2;
// quads 2,3 pull regs {2,3} from lane^32 via __shfl.
// LDS-only barrier + top-of-step register-double-buffered xg prefetch: global
// prefetches stay in flight across the barrier (no vmcnt(0) drain).
// ---------------------------------------------------------------------------
__global__ __launch_bounds__(512, 2) void lstm_scan(
    const bf16_t* __restrict__ xg2, const bf16_t* __restrict__ Whh,
    float* __restrict__ hT) {
  __shared__ __align__(16) bf16_t wlds[8 * 16 * 512];   // 128 KB
  __shared__ __align__(16) bf16_t hbuf[2][16][264];     // 16.9 KB

  const int tid = threadIdx.x;
  const int lane = tid & 63;
  const int w = tid >> 6;        // wave 0..7
  const int q = lane >> 4;
  const int l15 = lane & 15;
  const int b0 = blockIdx.x * 8;
  const int rq = (q & 1) * 4 + (q >> 1) * 2;   // this lane's row pair {rq,rq+1}
  const bool hi = (lane >= 32);                 // quads 2,3 pull from lane^32

  // ---- load W_hh: 6 (p,gate) sets -> VGPRs, (p=1, g=2,3) -> LDS ----
  bf16x8 wreg[6][8];
  #pragma unroll
  for (int p2 = 0; p2 < 2; ++p2) {
    #pragma unroll
    for (int g2 = 0; g2 < 4; ++g2) {
      const int j = p2 * 4 + g2;
      const bf16_t* src =
          Whh + (size_t)(g2 * 256 + 32 * w + 16 * p2 + l15) * H_ + q * 8;
      #pragma unroll
      for (int kk = 0; kk < 8; ++kk) {
        bf16x8 v = *(const bf16x8*)(src + kk * 32);
        if (j < 6) {
          wreg[j][kk] = v;
        } else {
          *(bf16x8*)&wlds[(size_t)((w * 16 + (g2 - 2) * 8 + kk)) * 512 + lane * 8] = v;
        }
      }
    }
  }

  for (int i = tid; i < 2 * 16 * 264; i += 512) ((bf16_t*)hbuf)[i] = (bf16_t)0.0f;
  __syncthreads();

  float cst[2][2];
  #pragma unroll
  for (int p = 0; p < 2; ++p) { cst[p][0] = 0.f; cst[p][1] = 0.f; }

  // xg pointers [phase][cell]; elem idx = row_g*T*1024 + t*1024 + c*4
  const bf16_t* xp[2][2];
  #pragma unroll
  for (int p = 0; p < 2; ++p)
    #pragma unroll
    for (int k = 0; k < 2; ++k)
      xp[p][k] = xg2 + (size_t)(b0 + rq + k) * (size_t)T_ * 1024 + (32 * w + 16 * p + l15) * 4;

  bf16x4 xv[2][2], xn[2][2];
  #pragma unroll
  for (int p = 0; p < 2; ++p)
    #pragma unroll
    for (int k = 0; k < 2; ++k) {
      xv[p][k] = *(const bf16x4*)xp[p][k];   // t=0
      xp[p][k] += 1024;                       // point at t=1
    }

  auto step = [&](int t, bf16x4 (&xc)[2][2], bf16x4 (&xf)[2][2]) {
    // prefetch t+1 at TOP of step (in flight across this step's barrier).
    // Last iter (t=1023) reads 2 KB past xg2 end -> lands in whhb region, unused.
    #pragma unroll
    for (int p = 0; p < 2; ++p)
      #pragma unroll
      for (int k = 0; k < 2; ++k) {
        xf[p][k] = *(const bf16x4*)xp[p][k];
        xp[p][k] += 1024;
      }
    const int cur = t & 1;
    #pragma unroll
    for (int p = 0; p < 2; ++p) {
      f32x4 acc[4];
      #pragma unroll
      for (int g = 0; g < 4; ++g) acc[g] = (f32x4){0.f, 0.f, 0.f, 0.f};
      #pragma unroll
      for (int kk = 0; kk < 8; ++kk) {
        bf16x8 a = *(const bf16x8*)&hbuf[cur][l15][kk * 32 + q * 8];
        if (p == 0) {
          acc[0] = __builtin_amdgcn_mfma_f32_16x16x32_bf16(a, wreg[0][kk], acc[0], 0, 0, 0);
          acc[1] = __builtin_amdgcn_mfma_f32_16x16x32_bf16(a, wreg[1][kk], acc[1], 0, 0, 0);
          acc[2] = __builtin_amdgcn_mfma_f32_16x16x32_bf16(a, wreg[2][kk], acc[2], 0, 0, 0);
          acc[3] = __builtin_amdgcn_mfma_f32_16x16x32_bf16(a, wreg[3][kk], acc[3], 0, 0, 0);
        } else {
          acc[0] = __builtin_amdgcn_mfma_f32_16x16x32_bf16(a, wreg[4][kk], acc[0], 0, 0, 0);
          acc[1] = __builtin_amdgcn_mfma_f32_16x16x32_bf16(a, wreg[5][kk], acc[1], 0, 0, 0);
          bf16x8 bg = *(const bf16x8*)&wlds[(size_t)(w * 16 + kk) * 512 + lane * 8];
          bf16x8 bo = *(const bf16x8*)&wlds[(size_t)(w * 16 + 8 + kk) * 512 + lane * 8];
          acc[2] = __builtin_amdgcn_mfma_f32_16x16x32_bf16(a, bg, acc[2], 0, 0, 0);
          acc[3] = __builtin_amdgcn_mfma_f32_16x16x32_bf16(a, bo, acc[3], 0, 0, 0);
        }
      }
      // redistribute: every lane ends with 2 cells (rows rq, rq+1)
      float G0[4], G1[4];
      #pragma unroll
      for (int g = 0; g < 4; ++g) {
        float s2 = __shfl(acc[g][2], lane ^ 32, 64);
        float s3 = __shfl(acc[g][3], lane ^ 32, 64);
        G0[g] = hi ? s2 : acc[g][0];
        G1[g] = hi ? s3 : acc[g][1];
      }
      const int c = 32 * w + 16 * p + l15;
      #pragma unroll
      for (int k = 0; k < 2; ++k) {
        const float* Gv_ = k ? G1 : G0;
        float gi = Gv_[0] + (float)xc[p][k][0];
        float gf = Gv_[1] + (float)xc[p][k][1];
        float gg = Gv_[2] + (float)xc[p][k][2];
        float go = Gv_[3] + (float)xc[p][k][3];
        float I = sigmoid_f(gi);
        float F = sigmoid_f(gf);
        float Gg = tanh_f(gg);
        float Ov = sigmoid_f(go);
        float cv = F * cst[p][k] + I * Gg;
        cst[p][k] = cv;
        float hv = Ov * tanh_f(cv);
        hbuf[cur ^ 1][rq + k][c] = (bf16_t)hv;
        if (t == T_ - 1) hT[(size_t)(b0 + rq + k) * H_ + c] = hv;
      }
    }
    barrier_lds_only();
  };

  #pragma unroll 1
  for (int t = 0; t < T_; t += 2) {
    step(t, xv, xn);
    step(t + 1, xn, xv);
  }
}

// ---------------------------------------------------------------------------
// out = h_T @ W_out^T + b_out   [128,256]x[256,128] -> tiny
// ---------------------------------------------------------------------------
__global__ __launch_bounds__(128) void head_gemm(
    const float* __restrict__ hT, const float* __restrict__ Wout,
    const float* __restrict__ bout, float* __restrict__ out) {
  __shared__ float hrow[H_];
  const int b = blockIdx.x;
  const int o = threadIdx.x;
  hrow[o] = hT[(size_t)b * H_ + o];
  hrow[o + 128] = hT[(size_t)b * H_ + 128 + o];
  __syncthreads();
  float s = bout[o];
  const float* wr = Wout + (size_t)o * H_;
  #pragma unroll 8
  for (int j = 0; j < H_; ++j) s += hrow[j] * wr[j];
  out[(size_t)b * 128 + o] = s;
}

// ---------------------------------------------------------------------------
extern "C" void kernel_launch(void* const* d_in, const int* in_sizes, int n_in,
                              void* d_out, int out_size, void* d_ws, size_t ws_size,
                              hipStream_t stream) {
  const float* X    = (const float*)d_in[0];
  const float* Wih  = (const float*)d_in[1];
  const float* Whh  = (const float*)d_in[2];
  const float* bih  = (const float*)d_in[3];
  const float* bhh  = (const float*)d_in[4];
  const float* Wout = (const float*)d_in[5];
  const float* bout = (const float*)d_in[6];
  float* out = (float*)d_out;

  // workspace layout (bytes)
  char* ws = (char*)d_ws;
  const size_t XG_BYTES   = (size_t)B_ * T_ * G_ * 2;        // 268435456
  const size_t WHHB_BYTES = (size_t)G_ * H_ * 2;             // 524288 (also prefetch slack)
  const size_t BIAS_BYTES = (size_t)G_ * 4;                  // 4096
  bf16_t* xg2  = (bf16_t*)ws;
  bf16_t* whhb = (bf16_t*)(ws + XG_BYTES);
  float*  bias = (float*)(ws + XG_BYTES + WHHB_BYTES);
  float*  hT   = (float*)(ws + XG_BYTES + WHHB_BYTES + BIAS_BYTES);

  prep_kernel<<<dim3(1024), 256, 0, stream>>>(Whh, bih, bhh, whhb, bias);
  xg_gemm<<<dim3((B_ * T_) / 64, 4), 256, 0, stream>>>(X, Wih, bias, xg2);
  lstm_scan<<<dim3(B_ / 8), 512, 0, stream>>>(xg2, whhb, hT);
  head_gemm<<<dim3(B_), 128, 0, stream>>>(hT, Wout, bout, out);
}